// Round 19
// baseline (218.606 us; speedup 1.0000x reference)
//
#include <hip/hip_runtime.h>
#include <cstddef>

// N=100000, E=800000, H=128, C=10, G=512
#define HD 128
#define QSEG 8      // partial-pool blocks per graph
#define BSH 7       // bucket shift: 128 dsts per bucket
#define NBP 1024    // padded bucket-array size (>= NB)
#define EB 4096     // edges per k_binP block
#define ECAP 1536   // padded slots per bucket (Poisson(1024)+16 sigma)

// Permuted storage layout for all hidden N x 128 arrays (M, Yb, Yf):
//   storage index s holds logical column c(s) = (s%8)*16 + s/8
// MFMA C/D fragment -> 8 contiguous f16 per (lane, r): coalesced 16B stores.
// Layer>=2 K relabeling is baked into the W fragments.
// All hidden values (M, Yb, Yf) are FP16.
// CSR is built in ONE pass into fixed-capacity bucket regions (ECAP each);
// rowptr/rowend are absolute indices into the padded csr_src.
// Packed edge encoding: u32 = (dst&127)<<20 | src, valid for N < 2^20.

typedef float f32x4 __attribute__((ext_vector_type(4)));
typedef float f32x8 __attribute__((ext_vector_type(8)));
typedef _Float16 f16x8 __attribute__((ext_vector_type(8)));
typedef unsigned short u16x8 __attribute__((ext_vector_type(8)));

static __device__ __forceinline__ int atomAddI(int* p, int v) {
    return __hip_atomic_fetch_add(p, v, __ATOMIC_RELAXED, __HIP_MEMORY_SCOPE_AGENT);
}

static __device__ __forceinline__ unsigned short f32_to_f16u(float f) {
    _Float16 h = (_Float16)f;  // v_cvt_f16_f32, RNE
    return __builtin_bit_cast(unsigned short, h);
}
static __device__ __forceinline__ float f16u_to_f32(unsigned short u) {
    return (float)__builtin_bit_cast(_Float16, u);
}

// cursor[b] = b * ECAP  (start of bucket b's padded region)
__global__ void k_initcur(int* cursor, int NB) {
    int i = blockIdx.x * blockDim.x + threadIdx.x;
    if (i < NB) cursor[i] = i * ECAP;
}

// Single-pass binning: edges -> bucket-grouped packed u32 in padded regions.
// Per-block LDS histogram, ONE reservation atomic per (block,bucket), then
// 4B writes into the reserved contiguous runs. No pre-scan needed.
__global__ __launch_bounds__(256) void k_binP(const int* __restrict__ rowi,
                                              const int* __restrict__ coli,
                                              int* __restrict__ cursor,
                                              unsigned* __restrict__ pairs, int E, int NB) {
    __shared__ int lcnt[NBP];
    __shared__ int gbs[NBP];
    const int t = threadIdx.x;
    const int base = blockIdx.x * EB;
    for (int b = t; b < NBP; b += 256) lcnt[b] = 0;
    __syncthreads();

    unsigned ed[16];
    int eb[16];
#pragma unroll
    for (int u = 0; u < 16; ++u) {
        const int idx = base + u * 256 + t;
        if (idx < E) {
            const unsigned src = (unsigned)rowi[idx];
            const unsigned dst = (unsigned)coli[idx];
            ed[u] = ((dst & 127u) << 20) | src;
            eb[u] = (int)(dst >> BSH);
            atomicAdd(&lcnt[eb[u]], 1);
        } else {
            eb[u] = -1;
        }
    }
    __syncthreads();
    for (int b = t; b < NB; b += 256) {
        const int c = lcnt[b];
        gbs[b] = c > 0 ? atomAddI(&cursor[b], c) : 0;
    }
    __syncthreads();
    for (int b = t; b < NBP; b += 256) lcnt[b] = 0;
    __syncthreads();
#pragma unroll
    for (int u = 0; u < 16; ++u) {
        if (eb[u] >= 0) {
            const int p = gbs[eb[u]] + atomicAdd(&lcnt[eb[u]], 1);
            pairs[p] = ed[u];
        }
    }
}

// One block per bucket: exact CSR (within the padded region) for 128 dsts.
// Writes absolute rowptr/rowend + dinv coalesced, then compacts srcs.
__global__ __launch_bounds__(256) void k_sortbuildP(const unsigned* __restrict__ pairs,
                                                    const int* __restrict__ cursor,
                                                    int* __restrict__ rowptr,
                                                    int* __restrict__ rowend,
                                                    float* __restrict__ dinv,
                                                    int* __restrict__ csr_src, int N) {
    __shared__ int cnt[128];
    __shared__ int pref[128];
    const int j = blockIdx.x;
    const int t = threadIdx.x;
    const int s = j * ECAP;
    const int e2 = cursor[j];          // end of this bucket's filled region
    const int d0 = j << BSH;
    const int dc = min(128, N - d0);

    if (t < 128) cnt[t] = 0;
    __syncthreads();
    for (int i = s + t; i < e2; i += 256)
        atomicAdd(&cnt[pairs[i] >> 20], 1);
    __syncthreads();
    if (t == 0) {
        int run = 0;
        for (int k = 0; k < 128; ++k) { pref[k] = run; run += cnt[k]; }
    }
    __syncthreads();
    if (t < dc) {
        rowptr[d0 + t] = s + pref[t];
        rowend[d0 + t] = s + pref[t] + cnt[t];
        dinv[d0 + t] = rsqrtf(1.0f + (float)cnt[t]);
    }
    __syncthreads();
    if (t < 128) cnt[t] = 0;
    __syncthreads();
    for (int i = s + t; i < e2; i += 256) {
        const unsigned p = pairs[i];
        const int dl = (int)(p >> 20);
        const int pos = atomicAdd(&cnt[dl], 1);
        csr_src[s + pref[dl] + pos] = (int)(p & 0xFFFFFu);
    }
}

// Precompute W into f16 MFMA B-fragment order (single table per layer).
// w==0 (layer 1, natural-layout A=x): k = kt*32 + (lane>>4)*8 + e.
// w>=1 (permuted-storage A):          k = e*16 + kt*4 + (lane>>4).
__global__ __launch_bounds__(256) void k_wfrag(const float* __restrict__ W1,
                                               const float* __restrict__ W2,
                                               const float* __restrict__ W3,
                                               unsigned short* __restrict__ wf) {
    const int w = blockIdx.x >> 3;
    const int slot = (blockIdx.x & 7) * 256 + threadIdx.x;  // 0..2047
    const int nt = slot >> 8;
    const int kt = (slot >> 6) & 3;
    const int lane = slot & 63;
    const float* W = (w == 0) ? W1 : (w == 1) ? W2 : W3;
    unsigned short* wt = wf + (size_t)w * 16384;
    const int obase = ((nt * 4 + kt) * 64 + lane) * 8;
    const int c = nt * 16 + (lane & 15);
    u16x8 h8;
#pragma unroll
    for (int e = 0; e < 8; ++e) {
        const int k = (w == 0) ? (kt * 32 + (lane >> 4) * 8 + e)
                               : (e * 16 + kt * 4 + (lane >> 4));
        h8[e] = f32_to_f16u(W[(size_t)k * HD + c]);
    }
    *(u16x8*)&wt[obase] = h8;
}

// Permute the three bias vectors into storage order: bp[s] = b[(s%8)*16 + s/8].
__global__ void k_bprep(const float* __restrict__ b1, const float* __restrict__ b2,
                        const float* __restrict__ b3, float* __restrict__ bp) {
    const int t = threadIdx.x;  // 128
    const float* b = (blockIdx.x == 0) ? b1 : (blockIdx.x == 1) ? b2 : b3;
    bp[blockIdx.x * HD + t] = b[(t & 7) * 16 + (t >> 3)];
}

// M = f16( dinv ⊙ (A @ W) ) in PERMUTED storage, via single f16 MFMA.
// Full f16 W table (32KB) staged once per block into LDS. Block = 4 waves
// covers 128 rows; each wave owns 32 rows as TWO independent chains.
// AF32=1: A f32 natural layout -> cvt f16.  AF32=0: A f16 permuted storage.
template <int AF32>
__global__ __launch_bounds__(256) void k_gemm(const void* __restrict__ Av,
                                              const unsigned short* __restrict__ wfr,
                                              const float* __restrict__ dinv,
                                              unsigned short* __restrict__ M, int n) {
    __shared__ unsigned short lds[16384];  // 32 KB f16 fragment table
    {
        const float4* s0 = (const float4*)wfr;  // 2048 float4
        float4* d0 = (float4*)lds;
#pragma unroll
        for (int i = 0; i < 8; ++i)
            d0[i * 256 + threadIdx.x] = s0[i * 256 + threadIdx.x];
    }
    __syncthreads();

    const int lane = threadIdx.x & 63;
    const int wid = threadIdx.x >> 6;
    const int rbase = blockIdx.x * 128 + wid * 32;
    const int arow0 = min(rbase + (lane & 15), n - 1);
    const int arow1 = min(rbase + 16 + (lane & 15), n - 1);
    const int kbase = (lane >> 4) * 8;

    f32x4 acc[2][8];
#pragma unroll
    for (int g = 0; g < 2; ++g)
#pragma unroll
        for (int nt = 0; nt < 8; ++nt) acc[g][nt] = (f32x4){0.f, 0.f, 0.f, 0.f};

#pragma unroll
    for (int kt = 0; kt < 4; ++kt) {
        f16x8 a0, a1;
        if (AF32) {
            const float* X = (const float*)Av;
            const float4 p0 = *(const float4*)&X[(size_t)arow0 * HD + kt * 32 + kbase];
            const float4 p1 = *(const float4*)&X[(size_t)arow0 * HD + kt * 32 + kbase + 4];
            const float4 q0 = *(const float4*)&X[(size_t)arow1 * HD + kt * 32 + kbase];
            const float4 q1 = *(const float4*)&X[(size_t)arow1 * HD + kt * 32 + kbase + 4];
            a0[0] = (_Float16)p0.x; a0[1] = (_Float16)p0.y;
            a0[2] = (_Float16)p0.z; a0[3] = (_Float16)p0.w;
            a0[4] = (_Float16)p1.x; a0[5] = (_Float16)p1.y;
            a0[6] = (_Float16)p1.z; a0[7] = (_Float16)p1.w;
            a1[0] = (_Float16)q0.x; a1[1] = (_Float16)q0.y;
            a1[2] = (_Float16)q0.z; a1[3] = (_Float16)q0.w;
            a1[4] = (_Float16)q1.x; a1[5] = (_Float16)q1.y;
            a1[6] = (_Float16)q1.z; a1[7] = (_Float16)q1.w;
        } else {
            const unsigned short* X = (const unsigned short*)Av;
            a0 = *(const f16x8*)&X[(size_t)arow0 * HD + kt * 32 + kbase];
            a1 = *(const f16x8*)&X[(size_t)arow1 * HD + kt * 32 + kbase];
        }
#pragma unroll
        for (int nt = 0; nt < 8; ++nt) {
            const int fo = ((nt * 4 + kt) * 64 + lane) * 8;
            const f16x8 bf = *(const f16x8*)&lds[fo];
            acc[0][nt] = __builtin_amdgcn_mfma_f32_16x16x32_f16(a0, bf, acc[0][nt], 0, 0, 0);
            acc[1][nt] = __builtin_amdgcn_mfma_f32_16x16x32_f16(a1, bf, acc[1][nt], 0, 0, 0);
        }
    }

    // C/D: row = (lane>>4)*4 + r, logical col = nt*16+(lane&15)
    //  -> storage s = (lane&15)*8 + nt  (contiguous over nt)
    const int colb = lane & 15;
    const int rq = (lane >> 4) * 4;
#pragma unroll
    for (int g = 0; g < 2; ++g) {
#pragma unroll
        for (int r = 0; r < 4; ++r) {
            const int row = rbase + g * 16 + rq + r;
            if (row < n) {
                const float d = dinv[row];
                u16x8 o;
#pragma unroll
                for (int nt = 0; nt < 8; ++nt) o[nt] = f32_to_f16u(acc[g][nt][r] * d);
                *(u16x8*)&M[(size_t)row * HD + colb * 8] = o;
            }
        }
    }
}

// OUT[i] = epi( dinv[i]*(M[i] + sum_{e in CSR[i]} M[src_e]) + b ),  M f16.
// 4 nodes per wave: each 16-lane group owns one node, reading full 256B rows
// as u16x8 (16B/lane). 4-edge unroll (VGPR ~28, ~61% occupancy — the 8-edge
// variant regressed: occupancy 41%). rowptr/rowend give [start,end) in the
// padded csr_src. RELU=1: relu. Output always f16 permuted storage.
template <int RELU>
__global__ __launch_bounds__(256) void k_gather(const int* __restrict__ rowptr,
                                                const int* __restrict__ rowend,
                                                const int* __restrict__ csr_src,
                                                const unsigned short* __restrict__ M,
                                                const float* __restrict__ dinv,
                                                const float* __restrict__ b,
                                                unsigned short* __restrict__ OUT, int n) {
    const int lane = threadIdx.x & 63;
    const int wid = threadIdx.x >> 6;
    const int grp = lane >> 4;
    const int node = blockIdx.x * 16 + wid * 4 + grp;
    if (node >= n) return;
    const int j = (lane & 15) * 8;  // f16 element offset (16B per lane)

    // self loop
    const u16x8 sv = *(const u16x8*)&M[(size_t)node * HD + j];
    f32x8 acc;
#pragma unroll
    for (int i = 0; i < 8; ++i) acc[i] = f16u_to_f32(sv[i]);

    const int s = rowptr[node];
    const int e = rowend[node];
    int k = s;
    for (; k + 4 <= e; k += 4) {
        const int i0 = csr_src[k], i1 = csr_src[k + 1];
        const int i2 = csr_src[k + 2], i3 = csr_src[k + 3];
        const u16x8 v0 = *(const u16x8*)&M[(size_t)i0 * HD + j];
        const u16x8 v1 = *(const u16x8*)&M[(size_t)i1 * HD + j];
        const u16x8 v2 = *(const u16x8*)&M[(size_t)i2 * HD + j];
        const u16x8 v3 = *(const u16x8*)&M[(size_t)i3 * HD + j];
#pragma unroll
        for (int i = 0; i < 8; ++i)
            acc[i] += (f16u_to_f32(v0[i]) + f16u_to_f32(v1[i])) +
                      (f16u_to_f32(v2[i]) + f16u_to_f32(v3[i]));
    }
    for (; k < e; ++k) {
        const int i0 = csr_src[k];
        const u16x8 v0 = *(const u16x8*)&M[(size_t)i0 * HD + j];
#pragma unroll
        for (int i = 0; i < 8; ++i) acc[i] += f16u_to_f32(v0[i]);
    }

    const float d = dinv[node];
    const float4 bv0 = *(const float4*)&b[j];
    const float4 bv1 = *(const float4*)&b[j + 4];
    const float bb[8] = {bv0.x, bv0.y, bv0.z, bv0.w, bv1.x, bv1.y, bv1.z, bv1.w};
    u16x8 ov;
#pragma unroll
    for (int i = 0; i < 8; ++i) {
        float o = fmaf(acc[i], d, bb[i]);
        if (RELU) o = fmaxf(o, 0.f);
        ov[i] = f32_to_f16u(o);
    }
    *(u16x8*)&OUT[(size_t)node * HD + j] = ov;
}

// Stage 1 pooling over f16 input: QSEG blocks per graph.
__global__ __launch_bounds__(128) void k_pool_part(const unsigned short* __restrict__ X,
                                                   const int* __restrict__ batch,
                                                   float* __restrict__ psum, int n) {
    const int g = blockIdx.x / QSEG;
    const int q = blockIdx.x % QSEG;
    const int t = threadIdx.x;
    int lo = 0, hi = n;
    while (lo < hi) { int m = (lo + hi) >> 1; if (batch[m] < g) lo = m + 1; else hi = m; }
    const int start = lo;
    hi = n;
    while (lo < hi) { int m = (lo + hi) >> 1; if (batch[m] < g + 1) lo = m + 1; else hi = m; }
    const int end = lo;
    float acc = 0.f;
    for (int i = start + q; i < end; i += QSEG)
        acc += f16u_to_f32(X[(size_t)i * HD + t]);
    psum[(size_t)blockIdx.x * HD + t] = acc;
}

// Stage 2 + final linear fused. pl is in permuted storage; map to logical
// column c(k) = (k%8)*16 + k/8 when indexing Wl.
__global__ __launch_bounds__(128) void k_pool_final(const float* __restrict__ psum,
                                                    const int* __restrict__ batch,
                                                    const float* __restrict__ Wl,
                                                    const float* __restrict__ bl,
                                                    float* __restrict__ out, int n, int C) {
    __shared__ float pl[HD];
    const int g = blockIdx.x;
    const int t = threadIdx.x;
    int lo = 0, hi = n;
    while (lo < hi) { int m = (lo + hi) >> 1; if (batch[m] < g) lo = m + 1; else hi = m; }
    const int start = lo;
    hi = n;
    while (lo < hi) { int m = (lo + hi) >> 1; if (batch[m] < g + 1) lo = m + 1; else hi = m; }
    const int cnt = lo - start;
    float acc = 0.f;
#pragma unroll
    for (int q = 0; q < QSEG; ++q)
        acc += psum[((size_t)g * QSEG + q) * HD + t];
    pl[t] = acc / (float)max(cnt, 1);
    __syncthreads();
    if (t < C) {
        float s = 0.f;
        for (int k = 0; k < HD; ++k) {
            const int c = (k & 7) * 16 + (k >> 3);
            s = fmaf(pl[k], Wl[(size_t)c * C + t], s);
        }
        out[(size_t)g * C + t] = s + bl[t];
    }
}

extern "C" void kernel_launch(void* const* d_in, const int* in_sizes, int n_in,
                              void* d_out, int out_size, void* d_ws, size_t ws_size,
                              hipStream_t stream) {
    const float* x   = (const float*)d_in[0];
    const int* ei    = (const int*)d_in[1];
    const int* batch = (const int*)d_in[2];
    const float* W1 = (const float*)d_in[3];
    const float* b1 = (const float*)d_in[4];
    const float* W2 = (const float*)d_in[5];
    const float* b2 = (const float*)d_in[6];
    const float* W3 = (const float*)d_in[7];
    const float* b3 = (const float*)d_in[8];
    const float* Wl = (const float*)d_in[9];
    const float* bl = (const float*)d_in[10];
    float* out = (float*)d_out;

    const int N = in_sizes[0] / HD;
    const int E = in_sizes[1] / 2;
    const int C = 10;
    const int G = out_size / C;
    const int NB = (N + 127) >> BSH;  // 128-dst buckets

    const int* rowi = ei;      // sources
    const int* coli = ei + E;  // targets

    // workspace layout
    unsigned short* Yf = (unsigned short*)d_ws;          // N*HD f16 (layer-3 out)
    unsigned short* M  = Yf + (size_t)N * HD;            // N*HD f16 messages
    unsigned short* Yb = M + (size_t)N * HD;             // N*HD f16 activations
    float* dinv     = (float*)(Yb + (size_t)N * HD);     // N
    unsigned short* wf = (unsigned short*)(dinv + N);    // 3*16384 f16 W tables
    float* bp       = (float*)(wf + 3 * 16384);          // 3*128 permuted biases
    int* rowptr     = (int*)(bp + 3 * HD);               // N
    int* rowend     = rowptr + N;                        // N
    int* cursor     = rowend + N;                        // NB
    int* csr_src    = cursor + NB;                       // NB*ECAP (padded)
    unsigned* pairs = (unsigned*)M;  // NB*ECAP u32 (4.8MB) — M unused until layer 1
    float* psum     = (float*)M;     // pooling scratch — M dead after layer-3 gather

    const int T = 256;

    // ---- preprocessing: single-pass padded CSR + dinv + W fragments ----
    k_initcur<<<(NB + T - 1) / T, T, 0, stream>>>(cursor, NB);
    k_binP<<<(E + EB - 1) / EB, T, 0, stream>>>(rowi, coli, cursor, pairs, E, NB);
    k_sortbuildP<<<NB, T, 0, stream>>>(pairs, cursor, rowptr, rowend, dinv, csr_src, N);
    k_wfrag<<<24, 256, 0, stream>>>(W1, W2, W3, wf);
    k_bprep<<<3, 128, 0, stream>>>(b1, b2, b3, bp);

    const unsigned short* wf1 = wf;
    const unsigned short* wf2 = wf + 16384;
    const unsigned short* wf3 = wf + 32768;

    const int gGemm   = (N + 127) / 128;
    const int gGather = (N + 15) / 16;

    // Layer 1: x(f32,natural) --gemm--> M(f16,perm) --gather--> Yb (f16, relu)
    k_gemm<1><<<gGemm, T, 0, stream>>>(x, wf1, dinv, M, N);
    k_gather<1><<<gGather, T, 0, stream>>>(rowptr, rowend, csr_src, M, dinv, bp, Yb, N);

    // Layer 2: Yb(f16,perm) --gemm--> M --gather--> Yb (f16, relu)
    k_gemm<0><<<gGemm, T, 0, stream>>>(Yb, wf2, dinv, M, N);
    k_gather<1><<<gGather, T, 0, stream>>>(rowptr, rowend, csr_src, M, dinv, bp + HD, Yb, N);

    // Layer 3: Yb(f16,perm) --gemm--> M --gather--> Yf (f16, no relu)
    k_gemm<0><<<gGemm, T, 0, stream>>>(Yb, wf3, dinv, M, N);
    k_gather<0><<<gGather, T, 0, stream>>>(rowptr, rowend, csr_src, M, dinv, bp + 2 * HD, Yf, N);

    // Two-stage pool + fused final linear (psum aliases M, now dead)
    k_pool_part<<<G * QSEG, 128, 0, stream>>>(Yf, batch, psum, N);
    k_pool_final<<<G, 128, 0, stream>>>(psum, batch, Wl, bl, out, N, C);
}